// Round 16
// baseline (81.427 us; speedup 1.0000x reference)
//
#include <hip/hip_runtime.h>
#include <hip/hip_bf16.h>

#define C_DIM 8192
#define E_DIM 512

using f32x4 = __attribute__((ext_vector_type(4))) float;
using i32x4 = __attribute__((ext_vector_type(4))) int;

__device__ inline void gload_lds16(const void* g, void* l) {
  __builtin_amdgcn_global_load_lds(
      (const __attribute__((address_space(1))) unsigned*)g,
      (__attribute__((address_space(3))) unsigned*)l, 16, 0, 0);
}

__device__ inline unsigned pack_bf16(float a, float b) {
  unsigned ua = __float_as_uint(a), ub = __float_as_uint(b);
  ua = (ua + 0x7fffu + ((ua >> 16) & 1u)) >> 16;
  ub = (ub + 0x7fffu + ((ub >> 16) & 1u)) >> 16;
  return ua | (ub << 16);
}

__device__ inline float bf2f(unsigned short u) {
  return __uint_as_float(((unsigned)u) << 16);
}

__device__ inline unsigned pack_i8x4(float a, float b, float c, float d) {
  unsigned x0 = (unsigned)(__float2int_rn(a * 127.f)) & 255u;
  unsigned x1 = (unsigned)(__float2int_rn(b * 127.f)) & 255u;
  unsigned x2 = (unsigned)(__float2int_rn(c * 127.f)) & 255u;
  unsigned x3 = (unsigned)(__float2int_rn(d * 127.f)) & 255u;
  return x0 | (x1 << 8) | (x2 << 16) | (x3 << 24);
}

// ------- Kernel 1: row L2 normalize -> bf16 + i8; block 0 zeroes flags ------
__global__ __launch_bounds__(256) void norm_kernel(
    const float* __restrict__ P, unsigned* __restrict__ Pb,
    unsigned* __restrict__ Pi, float* __restrict__ q,
    float* __restrict__ h_acc, unsigned* __restrict__ done) {
  if (blockIdx.x == 0) {
    int t = threadIdx.x;
    q[t] = 0.f;
    q[t + 256] = 0.f;
    if (t == 0) { h_acc[0] = 0.f; done[0] = 0u; }
  }
  int wid = threadIdx.x >> 6, lane = threadIdx.x & 63;
  int row = blockIdx.x * 4 + wid;
  const float4* src = (const float4*)(P + (size_t)row * E_DIM);
  float4 v0 = src[lane], v1 = src[lane + 64];
  float ss = v0.x * v0.x + v0.y * v0.y + v0.z * v0.z + v0.w * v0.w +
             v1.x * v1.x + v1.y * v1.y + v1.z * v1.z + v1.w * v1.w;
  for (int m = 32; m; m >>= 1) ss += __shfl_xor(ss, m);
  float inv = 1.0f / fmaxf(sqrtf(ss), 1e-12f);
  v0.x *= inv; v0.y *= inv; v0.z *= inv; v0.w *= inv;
  v1.x *= inv; v1.y *= inv; v1.z *= inv; v1.w *= inv;
  uint2* bd = (uint2*)(Pb + (size_t)row * (E_DIM / 2));
  uint2 b0, b1;
  b0.x = pack_bf16(v0.x, v0.y); b0.y = pack_bf16(v0.z, v0.w);
  b1.x = pack_bf16(v1.x, v1.y); b1.y = pack_bf16(v1.z, v1.w);
  bd[lane] = b0; bd[lane + 64] = b1;
  Pi[(size_t)row * 128 + lane] = pack_i8x4(v0.x, v0.y, v0.z, v0.w);
  Pi[(size_t)row * 128 + 64 + lane] = pack_i8x4(v1.x, v1.y, v1.z, v1.w);
}

// ---------------- Kernel 2: q = column sums of Pb (bf16) --------------------
__global__ __launch_bounds__(256) void qsum_kernel(
    const unsigned short* __restrict__ Pb, float* __restrict__ q) {
  __shared__ float red[4][512];
  int wid = threadIdx.x >> 6, lane = threadIdx.x & 63;
  float a[8];
#pragma unroll
  for (int k = 0; k < 8; ++k) a[k] = 0.f;
  for (int i = 0; i < 32; ++i) {
    int row = blockIdx.x * 128 + wid * 32 + i;
    uint4 v = *(const uint4*)(Pb + (size_t)row * E_DIM + lane * 8);
    a[0] += bf2f((unsigned short)(v.x & 0xffff));
    a[1] += bf2f((unsigned short)(v.x >> 16));
    a[2] += bf2f((unsigned short)(v.y & 0xffff));
    a[3] += bf2f((unsigned short)(v.y >> 16));
    a[4] += bf2f((unsigned short)(v.z & 0xffff));
    a[5] += bf2f((unsigned short)(v.z >> 16));
    a[6] += bf2f((unsigned short)(v.w & 0xffff));
    a[7] += bf2f((unsigned short)(v.w >> 16));
  }
#pragma unroll
  for (int k = 0; k < 8; ++k) red[wid][lane * 8 + k] = a[k];
  __syncthreads();
  for (int c = threadIdx.x; c < 512; c += 256) {
    float t = red[0][c] + red[1][c] + red[2][c] + red[3][c];
    atomicAdd(&q[c], t);
  }
}

// ---------------- Kernel 3: fused i8 Gram + exp-entropy partials ------------
// R14 verbatim: 128x128 upper-triangle tiles, 4 waves, 3 waves/SIMD, BK=128
// i8, XOR 16B-granule swizzle, both-sides-swizzled LDS-transpose epilogue.
__global__ __launch_bounds__(256, 3) void gram_kernel(
    const unsigned char* __restrict__ Pi, float* __restrict__ Zp,
    float* __restrict__ Sp) {
  __shared__ unsigned char As[128 * 128];  // 16 KB
  __shared__ unsigned char Bs[128 * 128];  // 16 KB

  // XCD-aware bijective remap (2080 = 8 * 260), then triangular decode
  int b = blockIdx.x;
  int i = (b & 7) * 260 + (b >> 3);
  float bi = 64.5f - sqrtf(64.5f * 64.5f - 2.0f * (float)i);
  int by = (int)bi;
  if (by < 0) by = 0;
  while (64 * (by + 1) - ((by + 1) * by) / 2 <= i) ++by;
  while (64 * by - (by * (by - 1)) / 2 > i) --by;
  int bx = by + (i - (64 * by - (by * (by - 1)) / 2));
  bool diag = (bx == by);

  int tid = threadIdx.x, wid = tid >> 6, lane = tid & 63;
  int wr = wid >> 1, wc = wid & 1;
  int l15 = lane & 15, lh = lane >> 4;

  i32x4 acc[4][4];
#pragma unroll
  for (int m = 0; m < 4; ++m)
#pragma unroll
    for (int n = 0; n < 4; ++n)
      acc[m][n] = (i32x4){0, 0, 0, 0};

  int rs = lane >> 3;               // row within 8-row chunk
  int gsw = (lane & 7) ^ rs;        // pre-swizzled 16B granule (XOR involution)
  const unsigned char* abase = Pi + (size_t)(by * 128) * E_DIM;
  const unsigned char* bbase = Pi + (size_t)(bx * 128) * E_DIM;

  for (int kt = 0; kt < 4; ++kt) {
#pragma unroll
    for (int j = 0; j < 4; ++j) {
      int ci = wid * 4 + j;  // 16 chunks of 8 rows
      int r = ci * 8 + rs;
      gload_lds16(abase + (size_t)r * E_DIM + kt * 128 + gsw * 16,
                  (char*)As + ci * 1024);
      gload_lds16(bbase + (size_t)r * E_DIM + kt * 128 + gsw * 16,
                  (char*)Bs + ci * 1024);
    }
    __syncthreads();

#pragma unroll
    for (int kk = 0; kk < 2; ++kk) {
      i32x4 af[4], bfr[4];
#pragma unroll
      for (int m = 0; m < 4; ++m) {
        int row = wr * 64 + m * 16 + l15;
        int g = (kk * 4 + lh) ^ (row & 7);
        af[m] = *(const i32x4*)(As + row * 128 + g * 16);
      }
#pragma unroll
      for (int n = 0; n < 4; ++n) {
        int row = wc * 64 + n * 16 + l15;
        int g = (kk * 4 + lh) ^ (row & 7);
        bfr[n] = *(const i32x4*)(Bs + row * 128 + g * 16);
      }
#pragma unroll
      for (int m = 0; m < 4; ++m)
#pragma unroll
        for (int n = 0; n < 4; ++n)
          acc[m][n] = __builtin_amdgcn_mfma_i32_16x16x64_i8(
              af[m], bfr[n], acc[m][n], 0, 0, 0);
    }
    if (kt < 3) __syncthreads();
  }

  // ---- epilogue: LDS-transpose row-reduce (both sides swizzled) ----
  __syncthreads();  // all LDS reads of As/Bs done -> reuse as fp32 buffers
  float* zb = (float*)As;  // [128 rows][32 slots], granule-swizzled
  float* sb = (float*)Bs;

  const float invq = 1.0f / 16129.0f;
  float zc[4], sc[4];
#pragma unroll
  for (int n = 0; n < 4; ++n) { zc[n] = 0.f; sc[n] = 0.f; }

#pragma unroll
  for (int m = 0; m < 4; ++m) {
#pragma unroll
    for (int reg = 0; reg < 4; ++reg) {
      float z = 0.f, s2 = 0.f;
#pragma unroll
      for (int n = 0; n < 4; ++n) {
        float g = (float)acc[m][n][reg] * invq;
        float e = __expf(g);
        z += e;
        s2 += e * g;
        zc[n] += e;
        sc[n] += e * g;
      }
      int row = wr * 64 + m * 16 + lh * 4 + reg;
      int gph = (wc * 4 + (l15 >> 2)) ^ (row & 7);  // swizzled 16B granule
      int idx = row * 32 + gph * 4 + (l15 & 3);
      zb[idx] = z;
      sb[idx] = s2;
    }
  }
  __syncthreads();

  // t<128 sums z of row t; t>=128 sums s. Reads de-swizzle per row.
  {
    int r = tid & 127;
    const float* buf = (tid >= 128) ? sb : zb;
    f32x4 a = {0.f, 0.f, 0.f, 0.f};
#pragma unroll
    for (int g = 0; g < 8; ++g)
      a += *(const f32x4*)(buf + r * 32 + ((g ^ (r & 7)) * 4));
    float tot = a[0] + a[1] + a[2] + a[3];
    int slotR = bx - by;
    size_t idx = (size_t)by * 16384 + (size_t)slotR * 128 + r;
    if (tid >= 128) Sp[idx] = tot; else Zp[idx] = tot;
  }

  if (!diag) {
    int slotC = (64 - bx) + 2 * by + wr;
#pragma unroll
    for (int n = 0; n < 4; ++n) {
      float z = zc[n], s2 = sc[n];
      z += __shfl_xor(z, 16); s2 += __shfl_xor(s2, 16);
      z += __shfl_xor(z, 32); s2 += __shfl_xor(s2, 32);
      if (lh == 0) {
        int colin = wc * 64 + n * 16 + l15;
        size_t idx = (size_t)bx * 16384 + (size_t)slotC * 128 + colin;
        Zp[idx] = z;
        Sp[idx] = s2;
      }
    }
  }
}

// --- Kernel 4: role-split: blocks 0..63 fold bands; 64..127 compute ssum ----
// ssum role writes s via AGENT-scope atomic stores (coherent across XCDs);
// done counts to 128; the 128th ticket (either role) runs finalize, reading s
// via AGENT-scope atomic loads. Pattern validated in R10 (q) / R9 (h_acc).
__global__ __launch_bounds__(256) void reduce_kernel(
    const float* __restrict__ Zp, const float* __restrict__ Sp,
    const unsigned short* __restrict__ Pb, const float* __restrict__ q,
    float* __restrict__ s, float* __restrict__ h_acc,
    unsigned* __restrict__ done, float* __restrict__ out) {
  __shared__ float zbuf[128], sbuf[128];
  __shared__ float red[8];
  __shared__ unsigned lastFlag;
  int t = threadIdx.x;
  int lane = t & 63, wid = t >> 6;

  if (blockIdx.x >= 64) {
    // ---------------- ssum role ----------------
    const float4* qv = (const float4*)q;
    float4 q0 = qv[lane * 2], q1 = qv[lane * 2 + 1];
    int base = (blockIdx.x - 64) * 128;
    for (int i = 0; i < 32; ++i) {
      int row = base + wid * 32 + i;
      uint4 v = *(const uint4*)(Pb + (size_t)row * E_DIM + lane * 8);
      float d = bf2f((unsigned short)(v.x & 0xffff)) * q0.x +
                bf2f((unsigned short)(v.x >> 16)) * q0.y +
                bf2f((unsigned short)(v.y & 0xffff)) * q0.z +
                bf2f((unsigned short)(v.y >> 16)) * q0.w +
                bf2f((unsigned short)(v.z & 0xffff)) * q1.x +
                bf2f((unsigned short)(v.z >> 16)) * q1.y +
                bf2f((unsigned short)(v.w & 0xffff)) * q1.z +
                bf2f((unsigned short)(v.w >> 16)) * q1.w;
      for (int m = 32; m; m >>= 1) d += __shfl_xor(d, m);
      if (lane == 0)
        __hip_atomic_store(&s[row], d, __ATOMIC_RELAXED,
                           __HIP_MEMORY_SCOPE_AGENT);
    }
    __syncthreads();  // all waves' stores drained (vmcnt) before ticket
    if (t == 0) {
      __threadfence();
      unsigned old = atomicAdd(done, 1u);
      lastFlag = (old == 127u) ? 1u : 0u;
    }
    __syncthreads();
  } else {
    // ---------------- band-fold role ----------------
    int rb = blockIdx.x;
    int row = t & 127;
    const float* src = (t >= 128) ? Sp : Zp;
    size_t base = (size_t)rb * 16384 + row;
    float acc = 0.f;
    int nsl = 64 + rb;  // row slots (64-rb) + col slots (2*rb)
#pragma unroll 4
    for (int sl = 0; sl < nsl; ++sl) acc += src[base + (size_t)sl * 128];
    if (t >= 128) sbuf[row] = acc; else zbuf[row] = acc;
    __syncthreads();

    float hp = 0.f;
    if (t < 128) {
      float z = zbuf[t], s2 = sbuf[t];
      hp = logf(z) - s2 / z;
    }
    for (int k = 32; k; k >>= 1) hp += __shfl_xor(hp, k);
    if (lane == 0) red[wid] = hp;
    __syncthreads();
    if (t == 0) {
      float h = red[0] + red[1];
      atomicAdd(h_acc, h);
      __threadfence();
      unsigned old = atomicAdd(done, 1u);
      lastFlag = (old == 127u) ? 1u : 0u;
    }
    __syncthreads();
  }

  if (lastFlag) {
    // H2 = entropy of softmax(s); s read with agent-scope atomic loads
    float m = -3.4e38f;
    for (int i = t; i < C_DIM; i += 256)
      m = fmaxf(m, __hip_atomic_load(&s[i], __ATOMIC_RELAXED,
                                     __HIP_MEMORY_SCOPE_AGENT));
    for (int k = 32; k; k >>= 1) m = fmaxf(m, __shfl_xor(m, k));
    if (lane == 0) red[wid] = m;
    __syncthreads();
    m = fmaxf(fmaxf(red[0], red[1]), fmaxf(red[2], red[3]));

    float z = 0.f, sw = 0.f;
    for (int i = t; i < C_DIM; i += 256) {
      float tv = __hip_atomic_load(&s[i], __ATOMIC_RELAXED,
                                   __HIP_MEMORY_SCOPE_AGENT) - m;
      float e = __expf(tv);
      z += e;
      sw += e * tv;
    }
    for (int k = 32; k; k >>= 1) {
      z += __shfl_xor(z, k);
      sw += __shfl_xor(sw, k);
    }
    __syncthreads();
    if (lane == 0) { red[wid] = z; red[4 + wid] = sw; }
    __syncthreads();
    if (t == 0) {
      float zt = red[0] + red[1] + red[2] + red[3];
      float st = red[4] + red[5] + red[6] + red[7];
      float H2 = logf(zt) - st / zt;
      float h = atomicAdd(h_acc, 0.0f);  // coherent read of final sum
      out[0] = h / (float)C_DIM + H2;
    }
  }
}

extern "C" void kernel_launch(void* const* d_in, const int* in_sizes, int n_in,
                              void* d_out, int out_size, void* d_ws, size_t ws_size,
                              hipStream_t stream) {
  const float* P = (const float*)d_in[0];
  float* out = (float*)d_out;

  char* ws = (char*)d_ws;
  unsigned* Pb = (unsigned*)ws;                                  // 8 MB bf16
  unsigned* Pi = (unsigned*)(ws + ((size_t)8 << 20));            // 4 MB i8
  float* Zp = (float*)(ws + ((size_t)12 << 20));                 // 4 MB
  float* Sp = (float*)(ws + ((size_t)16 << 20));                 // 4 MB
  float* q = (float*)(ws + ((size_t)20 << 20));                  // 2 KB
  float* h_acc = (float*)(ws + ((size_t)20 << 20) + 2048);       // 4 B
  unsigned* done = (unsigned*)(ws + ((size_t)20 << 20) + 2052);  // 4 B
  float* s = (float*)(ws + ((size_t)20 << 20) + 4096);           // 32 KB

  norm_kernel<<<C_DIM / 4, 256, 0, stream>>>(P, Pb, Pi, q, h_acc, done);
  qsum_kernel<<<C_DIM / 128, 256, 0, stream>>>((const unsigned short*)Pb, q);
  gram_kernel<<<2080, 256, 0, stream>>>((const unsigned char*)Pi, Zp, Sp);
  reduce_kernel<<<128, 256, 0, stream>>>(Zp, Sp, (const unsigned short*)Pb, q,
                                         s, h_acc, done, out);
}

// Round 17
// 70.391 us; speedup vs baseline: 1.1568x; 1.1568x over previous
//
#include <hip/hip_runtime.h>
#include <hip/hip_bf16.h>

#define C_DIM 8192
#define E_DIM 512

using f32x4 = __attribute__((ext_vector_type(4))) float;
using i32x4 = __attribute__((ext_vector_type(4))) int;

__device__ inline void gload_lds16(const void* g, void* l) {
  __builtin_amdgcn_global_load_lds(
      (const __attribute__((address_space(1))) unsigned*)g,
      (__attribute__((address_space(3))) unsigned*)l, 16, 0, 0);
}

__device__ inline unsigned pack_bf16(float a, float b) {
  unsigned ua = __float_as_uint(a), ub = __float_as_uint(b);
  ua = (ua + 0x7fffu + ((ua >> 16) & 1u)) >> 16;
  ub = (ub + 0x7fffu + ((ub >> 16) & 1u)) >> 16;
  return ua | (ub << 16);
}

__device__ inline float bf2f(unsigned short u) {
  return __uint_as_float(((unsigned)u) << 16);
}

__device__ inline unsigned pack_i8x4(float a, float b, float c, float d) {
  unsigned x0 = (unsigned)(__float2int_rn(a * 127.f)) & 255u;
  unsigned x1 = (unsigned)(__float2int_rn(b * 127.f)) & 255u;
  unsigned x2 = (unsigned)(__float2int_rn(c * 127.f)) & 255u;
  unsigned x3 = (unsigned)(__float2int_rn(d * 127.f)) & 255u;
  return x0 | (x1 << 8) | (x2 << 16) | (x3 << 24);
}

// ------- Kernel 1: row L2 normalize -> bf16 + i8; block 0 zeroes flags ------
__global__ __launch_bounds__(256) void norm_kernel(
    const float* __restrict__ P, unsigned* __restrict__ Pb,
    unsigned* __restrict__ Pi, float* __restrict__ q,
    float* __restrict__ h_acc, unsigned* __restrict__ done) {
  if (blockIdx.x == 0) {
    int t = threadIdx.x;
    q[t] = 0.f;
    q[t + 256] = 0.f;
    if (t == 0) { h_acc[0] = 0.f; done[0] = 0u; }
  }
  int wid = threadIdx.x >> 6, lane = threadIdx.x & 63;
  int row = blockIdx.x * 4 + wid;
  const float4* src = (const float4*)(P + (size_t)row * E_DIM);
  float4 v0 = src[lane], v1 = src[lane + 64];
  float ss = v0.x * v0.x + v0.y * v0.y + v0.z * v0.z + v0.w * v0.w +
             v1.x * v1.x + v1.y * v1.y + v1.z * v1.z + v1.w * v1.w;
  for (int m = 32; m; m >>= 1) ss += __shfl_xor(ss, m);
  float inv = 1.0f / fmaxf(sqrtf(ss), 1e-12f);
  v0.x *= inv; v0.y *= inv; v0.z *= inv; v0.w *= inv;
  v1.x *= inv; v1.y *= inv; v1.z *= inv; v1.w *= inv;
  uint2* bd = (uint2*)(Pb + (size_t)row * (E_DIM / 2));
  uint2 b0, b1;
  b0.x = pack_bf16(v0.x, v0.y); b0.y = pack_bf16(v0.z, v0.w);
  b1.x = pack_bf16(v1.x, v1.y); b1.y = pack_bf16(v1.z, v1.w);
  bd[lane] = b0; bd[lane + 64] = b1;
  Pi[(size_t)row * 128 + lane] = pack_i8x4(v0.x, v0.y, v0.z, v0.w);
  Pi[(size_t)row * 128 + 64 + lane] = pack_i8x4(v1.x, v1.y, v1.z, v1.w);
}

// ---------------- Kernel 2: q = column sums of Pb (bf16) --------------------
__global__ __launch_bounds__(256) void qsum_kernel(
    const unsigned short* __restrict__ Pb, float* __restrict__ q) {
  __shared__ float red[4][512];
  int wid = threadIdx.x >> 6, lane = threadIdx.x & 63;
  float a[8];
#pragma unroll
  for (int k = 0; k < 8; ++k) a[k] = 0.f;
  for (int i = 0; i < 32; ++i) {
    int row = blockIdx.x * 128 + wid * 32 + i;
    uint4 v = *(const uint4*)(Pb + (size_t)row * E_DIM + lane * 8);
    a[0] += bf2f((unsigned short)(v.x & 0xffff));
    a[1] += bf2f((unsigned short)(v.x >> 16));
    a[2] += bf2f((unsigned short)(v.y & 0xffff));
    a[3] += bf2f((unsigned short)(v.y >> 16));
    a[4] += bf2f((unsigned short)(v.z & 0xffff));
    a[5] += bf2f((unsigned short)(v.z >> 16));
    a[6] += bf2f((unsigned short)(v.w & 0xffff));
    a[7] += bf2f((unsigned short)(v.w >> 16));
  }
#pragma unroll
  for (int k = 0; k < 8; ++k) red[wid][lane * 8 + k] = a[k];
  __syncthreads();
  for (int c = threadIdx.x; c < 512; c += 256) {
    float t = red[0][c] + red[1][c] + red[2][c] + red[3][c];
    atomicAdd(&q[c], t);
  }
}

// ---------------- Kernel 3: s_j = dot(Pb[j], q) -----------------------------
__global__ __launch_bounds__(256) void ssum_kernel(
    const unsigned short* __restrict__ Pb, const float* __restrict__ q,
    float* __restrict__ s) {
  int wid = threadIdx.x >> 6, lane = threadIdx.x & 63;
  int row = blockIdx.x * 4 + wid;
  uint4 v = *(const uint4*)(Pb + (size_t)row * E_DIM + lane * 8);
  const float4* qv = (const float4*)q;
  float4 q0 = qv[lane * 2], q1 = qv[lane * 2 + 1];
  float d = bf2f((unsigned short)(v.x & 0xffff)) * q0.x +
            bf2f((unsigned short)(v.x >> 16)) * q0.y +
            bf2f((unsigned short)(v.y & 0xffff)) * q0.z +
            bf2f((unsigned short)(v.y >> 16)) * q0.w +
            bf2f((unsigned short)(v.z & 0xffff)) * q1.x +
            bf2f((unsigned short)(v.z >> 16)) * q1.y +
            bf2f((unsigned short)(v.w & 0xffff)) * q1.z +
            bf2f((unsigned short)(v.w >> 16)) * q1.w;
  for (int m = 32; m; m >>= 1) d += __shfl_xor(d, m);
  if (lane == 0) s[row] = d;
}

// ---------------- Kernel 4: fused i8 Gram + exp-entropy partials ------------
// Best measured structure: 128x128 upper-triangle tiles, 4 waves, 3
// waves/SIMD, BK=128 i8 -> 4 K-steps, 16+16 KB LDS, XOR 16B-granule swizzle
// (pre-swizzled global source + swizzled reads), LDS-transpose epilogue with
// both sides swizzled, write-once slice layout (no atomics, no zero-init).
__global__ __launch_bounds__(256, 3) void gram_kernel(
    const unsigned char* __restrict__ Pi, float* __restrict__ Zp,
    float* __restrict__ Sp) {
  __shared__ unsigned char As[128 * 128];  // 16 KB
  __shared__ unsigned char Bs[128 * 128];  // 16 KB

  // XCD-aware bijective remap (2080 = 8 * 260), then triangular decode
  int b = blockIdx.x;
  int i = (b & 7) * 260 + (b >> 3);
  float bi = 64.5f - sqrtf(64.5f * 64.5f - 2.0f * (float)i);
  int by = (int)bi;
  if (by < 0) by = 0;
  while (64 * (by + 1) - ((by + 1) * by) / 2 <= i) ++by;
  while (64 * by - (by * (by - 1)) / 2 > i) --by;
  int bx = by + (i - (64 * by - (by * (by - 1)) / 2));
  bool diag = (bx == by);

  int tid = threadIdx.x, wid = tid >> 6, lane = tid & 63;
  int wr = wid >> 1, wc = wid & 1;
  int l15 = lane & 15, lh = lane >> 4;

  i32x4 acc[4][4];
#pragma unroll
  for (int m = 0; m < 4; ++m)
#pragma unroll
    for (int n = 0; n < 4; ++n)
      acc[m][n] = (i32x4){0, 0, 0, 0};

  int rs = lane >> 3;               // row within 8-row chunk
  int gsw = (lane & 7) ^ rs;        // pre-swizzled 16B granule (XOR involution)
  const unsigned char* abase = Pi + (size_t)(by * 128) * E_DIM;
  const unsigned char* bbase = Pi + (size_t)(bx * 128) * E_DIM;

  for (int kt = 0; kt < 4; ++kt) {
#pragma unroll
    for (int j = 0; j < 4; ++j) {
      int ci = wid * 4 + j;  // 16 chunks of 8 rows
      int r = ci * 8 + rs;
      gload_lds16(abase + (size_t)r * E_DIM + kt * 128 + gsw * 16,
                  (char*)As + ci * 1024);
      gload_lds16(bbase + (size_t)r * E_DIM + kt * 128 + gsw * 16,
                  (char*)Bs + ci * 1024);
    }
    __syncthreads();

#pragma unroll
    for (int kk = 0; kk < 2; ++kk) {
      i32x4 af[4], bfr[4];
#pragma unroll
      for (int m = 0; m < 4; ++m) {
        int row = wr * 64 + m * 16 + l15;
        int g = (kk * 4 + lh) ^ (row & 7);
        af[m] = *(const i32x4*)(As + row * 128 + g * 16);
      }
#pragma unroll
      for (int n = 0; n < 4; ++n) {
        int row = wc * 64 + n * 16 + l15;
        int g = (kk * 4 + lh) ^ (row & 7);
        bfr[n] = *(const i32x4*)(Bs + row * 128 + g * 16);
      }
#pragma unroll
      for (int m = 0; m < 4; ++m)
#pragma unroll
        for (int n = 0; n < 4; ++n)
          acc[m][n] = __builtin_amdgcn_mfma_i32_16x16x64_i8(
              af[m], bfr[n], acc[m][n], 0, 0, 0);
    }
    if (kt < 3) __syncthreads();
  }

  // ---- epilogue: LDS-transpose row-reduce (both sides swizzled) ----
  __syncthreads();  // all LDS reads of As/Bs done -> reuse as fp32 buffers
  float* zb = (float*)As;  // [128 rows][32 slots], granule-swizzled
  float* sb = (float*)Bs;

  const float invq = 1.0f / 16129.0f;
  float zc[4], sc[4];
#pragma unroll
  for (int n = 0; n < 4; ++n) { zc[n] = 0.f; sc[n] = 0.f; }

#pragma unroll
  for (int m = 0; m < 4; ++m) {
#pragma unroll
    for (int reg = 0; reg < 4; ++reg) {
      float z = 0.f, s2 = 0.f;
#pragma unroll
      for (int n = 0; n < 4; ++n) {
        float g = (float)acc[m][n][reg] * invq;
        float e = __expf(g);
        z += e;
        s2 += e * g;
        zc[n] += e;
        sc[n] += e * g;
      }
      int row = wr * 64 + m * 16 + lh * 4 + reg;
      int gph = (wc * 4 + (l15 >> 2)) ^ (row & 7);  // swizzled 16B granule
      int idx = row * 32 + gph * 4 + (l15 & 3);
      zb[idx] = z;
      sb[idx] = s2;
    }
  }
  __syncthreads();

  // t<128 sums z of row t; t>=128 sums s. Reads de-swizzle per row
  // (g ^ (r&7)) so lanes spread over all banks (b128 8-phase floor).
  {
    int r = tid & 127;
    const float* buf = (tid >= 128) ? sb : zb;
    f32x4 a = {0.f, 0.f, 0.f, 0.f};
#pragma unroll
    for (int g = 0; g < 8; ++g)
      a += *(const f32x4*)(buf + r * 32 + ((g ^ (r & 7)) * 4));
    float tot = a[0] + a[1] + a[2] + a[3];
    int slotR = bx - by;
    size_t idx = (size_t)by * 16384 + (size_t)slotR * 128 + r;
    if (tid >= 128) Sp[idx] = tot; else Zp[idx] = tot;
  }

  if (!diag) {
    int slotC = (64 - bx) + 2 * by + wr;
#pragma unroll
    for (int n = 0; n < 4; ++n) {
      float z = zc[n], s2 = sc[n];
      z += __shfl_xor(z, 16); s2 += __shfl_xor(s2, 16);
      z += __shfl_xor(z, 32); s2 += __shfl_xor(s2, 32);
      if (lh == 0) {
        int colin = wc * 64 + n * 16 + l15;
        size_t idx = (size_t)bx * 16384 + (size_t)slotC * 128 + colin;
        Zp[idx] = z;
        Sp[idx] = s2;
      }
    }
  }
}

// ------- Kernel 5: fold slices -> per-row entropy; last block finalizes -----
__global__ __launch_bounds__(256) void reduce_kernel(
    const float* __restrict__ Zp, const float* __restrict__ Sp,
    const float* __restrict__ s, float* __restrict__ h_acc,
    unsigned* __restrict__ done, float* __restrict__ out) {
  __shared__ float zbuf[128], sbuf[128];
  __shared__ float red[8];
  __shared__ unsigned lastFlag;
  int rb = blockIdx.x;
  int t = threadIdx.x;
  int lane = t & 63, wid = t >> 6;
  int row = t & 127;
  const float* src = (t >= 128) ? Sp : Zp;
  size_t base = (size_t)rb * 16384 + row;
  float acc = 0.f;
  int nsl = 64 + rb;  // row slots (64-rb) + col slots (2*rb)
#pragma unroll 4
  for (int sl = 0; sl < nsl; ++sl) acc += src[base + (size_t)sl * 128];
  if (t >= 128) sbuf[row] = acc; else zbuf[row] = acc;
  __syncthreads();

  float hp = 0.f;
  if (t < 128) {
    float z = zbuf[t], s2 = sbuf[t];
    hp = logf(z) - s2 / z;
  }
  for (int k = 32; k; k >>= 1) hp += __shfl_xor(hp, k);
  if (lane == 0) red[wid] = hp;
  __syncthreads();
  if (t == 0) {
    float h = red[0] + red[1];
    atomicAdd(h_acc, h);
    __threadfence();
    unsigned old = atomicAdd(done, 1u);
    lastFlag = (old == 63u) ? 1u : 0u;
  }
  __syncthreads();

  if (lastFlag) {
    float m = -3.4e38f;
    for (int i = t; i < C_DIM; i += 256) m = fmaxf(m, s[i]);
    for (int k = 32; k; k >>= 1) m = fmaxf(m, __shfl_xor(m, k));
    if (lane == 0) red[wid] = m;
    __syncthreads();
    m = fmaxf(fmaxf(red[0], red[1]), fmaxf(red[2], red[3]));

    float z = 0.f, sw = 0.f;
    for (int i = t; i < C_DIM; i += 256) {
      float tv = s[i] - m;
      float e = __expf(tv);
      z += e;
      sw += e * tv;
    }
    for (int k = 32; k; k >>= 1) {
      z += __shfl_xor(z, k);
      sw += __shfl_xor(sw, k);
    }
    __syncthreads();
    if (lane == 0) { red[wid] = z; red[4 + wid] = sw; }
    __syncthreads();
    if (t == 0) {
      float zt = red[0] + red[1] + red[2] + red[3];
      float st = red[4] + red[5] + red[6] + red[7];
      float H2 = logf(zt) - st / zt;
      float h = atomicAdd(h_acc, 0.0f);  // coherent read of final sum
      out[0] = h / (float)C_DIM + H2;
    }
  }
}

extern "C" void kernel_launch(void* const* d_in, const int* in_sizes, int n_in,
                              void* d_out, int out_size, void* d_ws, size_t ws_size,
                              hipStream_t stream) {
  const float* P = (const float*)d_in[0];
  float* out = (float*)d_out;

  char* ws = (char*)d_ws;
  unsigned* Pb = (unsigned*)ws;                                  // 8 MB bf16
  unsigned* Pi = (unsigned*)(ws + ((size_t)8 << 20));            // 4 MB i8
  float* Zp = (float*)(ws + ((size_t)12 << 20));                 // 4 MB
  float* Sp = (float*)(ws + ((size_t)16 << 20));                 // 4 MB
  float* q = (float*)(ws + ((size_t)20 << 20));                  // 2 KB
  float* h_acc = (float*)(ws + ((size_t)20 << 20) + 2048);       // 4 B
  unsigned* done = (unsigned*)(ws + ((size_t)20 << 20) + 2052);  // 4 B
  float* s = (float*)(ws + ((size_t)20 << 20) + 4096);           // 32 KB

  norm_kernel<<<C_DIM / 4, 256, 0, stream>>>(P, Pb, Pi, q, h_acc, done);
  qsum_kernel<<<C_DIM / 128, 256, 0, stream>>>((const unsigned short*)Pb, q);
  ssum_kernel<<<C_DIM / 4, 256, 0, stream>>>((const unsigned short*)Pb, q, s);
  gram_kernel<<<2080, 256, 0, stream>>>((const unsigned char*)Pi, Zp, Sp);
  reduce_kernel<<<64, 256, 0, stream>>>(Zp, Sp, s, h_acc, done, out);
}